// Round 1
// baseline (2014.708 us; speedup 1.0000x reference)
//
#include <hip/hip_runtime.h>
#include <math.h>

#define BB 4
#define LL 2048
#define HH 8
#define EE 64
#define TM 64
#define TN 64

static constexpr float SCALE = 0.125f;                    // 1/sqrt(64)
static constexpr float LN3 = 1.0986122886681098f;
static constexpr float INV_SQRT_2PI = 0.3989422804014327f;
static constexpr size_t NMAT = (size_t)BB * HH * LL * LL;
static constexpr size_t SERIES_BASE = (size_t)BB * LL * HH * EE;
static constexpr size_t PRIOR_BASE = SERIES_BASE + NMAT;
static constexpr size_t SIG_BASE = PRIOR_BASE + NMAT;

__device__ __forceinline__ float dot4(float4 a, float4 b) {
  return a.x * b.x + a.y * b.y + a.z * b.z + a.w * b.w;
}
__device__ __forceinline__ void fma4(float4& acc, float s, float4 v) {
  acc.x += s * v.x; acc.y += s * v.y; acc.z += s * v.z; acc.w += s * v.w;
}

__global__ __launch_bounds__(256, 3)
void anomaly_attn(const float* __restrict__ qg,
                  const float* __restrict__ kg,
                  const float* __restrict__ vg,
                  const float* __restrict__ sgg,
                  float* __restrict__ out) {
  // LDS: Q tile, K tile (aliased by P tile after S-compute), V tile.
  // Row stride 17 float4 (68 dwords): all hot read patterns are <=2-way bank aliased.
  __shared__ float4 Qs[TM][17];
  __shared__ float4 KPs[TN][17];   // K tile; after S-compute reused as P (float[64][68])
  __shared__ float4 Vs[TN][17];
  __shared__ float s_linv[TM];
  __shared__ float s_sigv[TM], s_pinv[TM], s_c2[TM];

  const int t = threadIdx.x;
  const int bh = blockIdx.y;        // 0..31
  const int b = bh >> 3;            // H == 8
  const int h = bh & 7;
  const int tx = t & 15;            // column / e-chunk lane
  const int ty = t >> 4;            // row-group 0..15

  const float4* q4 = (const float4*)qg;
  const float4* k4 = (const float4*)kg;
  const float4* v4 = (const float4*)vg;
  float* Pf = (float*)&KPs[0][0];   // P: row stride 68 dwords

  // Triangular balance: pair row-tile x with 31-x (uniform 33 j-tiles per pass).
  for (int half = 0; half < 2; ++half) {
    const int rt = (half == 0) ? (int)blockIdx.x : (LL / TM - 1 - (int)blockIdx.x);
    const int i0 = rt * TM;
    const int nt = rt + 1;          // causal j-tiles

    __syncthreads();                // protect LDS from previous half

    // ---- load Q tile (64 rows x 16 float4) ----
    for (int idx = t; idx < TM * 16; idx += 256) {
      int r = idx >> 4, c = idx & 15;
      Qs[r][c] = q4[(((size_t)b * LL + (i0 + r)) * HH + h) * 16 + c];
    }
    // ---- per-row sigma transform ----
    if (t < TM) {
      float sg = sgg[((size_t)b * LL + (i0 + t)) * HH + h];
      float sd = 1.0f / (1.0f + __expf(-5.0f * sg)) + 1e-5f;
      float sv = expm1f(sd * LN3);  // 3^sd - 1, cancellation-safe
      s_sigv[t] = sv;
      s_pinv[t] = INV_SQRT_2PI / sv;
      s_c2[t] = 0.5f / (sv * sv);
    }

    // ================= pass 1: row sums of exp(scale*s) =================
    float lr0 = 0.f, lr1 = 0.f, lr2 = 0.f, lr3 = 0.f;
    for (int jt = 0; jt < nt; ++jt) {
      const int j0 = jt * TN;
      __syncthreads();
      for (int idx = t; idx < TN * 16; idx += 256) {
        int r = idx >> 4, c = idx & 15;
        KPs[r][c] = k4[(((size_t)b * LL + (j0 + r)) * HH + h) * 16 + c];
      }
      __syncthreads();
      float S[4][4] = {};
      for (int e4 = 0; e4 < 16; ++e4) {
        float4 qv0 = Qs[ty][e4];
        float4 qv1 = Qs[ty + 16][e4];
        float4 qv2 = Qs[ty + 32][e4];
        float4 qv3 = Qs[ty + 48][e4];
        float4 kv0 = KPs[tx][e4];
        float4 kv1 = KPs[tx + 16][e4];
        float4 kv2 = KPs[tx + 32][e4];
        float4 kv3 = KPs[tx + 48][e4];
        S[0][0] += dot4(qv0, kv0); S[0][1] += dot4(qv0, kv1);
        S[0][2] += dot4(qv0, kv2); S[0][3] += dot4(qv0, kv3);
        S[1][0] += dot4(qv1, kv0); S[1][1] += dot4(qv1, kv1);
        S[1][2] += dot4(qv1, kv2); S[1][3] += dot4(qv1, kv3);
        S[2][0] += dot4(qv2, kv0); S[2][1] += dot4(qv2, kv1);
        S[2][2] += dot4(qv2, kv2); S[2][3] += dot4(qv2, kv3);
        S[3][0] += dot4(qv3, kv0); S[3][1] += dot4(qv3, kv1);
        S[3][2] += dot4(qv3, kv2); S[3][3] += dot4(qv3, kv3);
      }
#pragma unroll
      for (int cc = 0; cc < 4; ++cc) {
        int j = j0 + tx + 16 * cc;
        lr0 += (j <= i0 + ty)      ? __expf(S[0][cc] * SCALE) : 0.f;
        lr1 += (j <= i0 + ty + 16) ? __expf(S[1][cc] * SCALE) : 0.f;
        lr2 += (j <= i0 + ty + 32) ? __expf(S[2][cc] * SCALE) : 0.f;
        lr3 += (j <= i0 + ty + 48) ? __expf(S[3][cc] * SCALE) : 0.f;
      }
    }
    // reduce across the 16 tx lanes of each ty group (all within one wave)
#pragma unroll
    for (int m = 1; m < 16; m <<= 1) {
      lr0 += __shfl_xor(lr0, m);
      lr1 += __shfl_xor(lr1, m);
      lr2 += __shfl_xor(lr2, m);
      lr3 += __shfl_xor(lr3, m);
    }
    if (tx == 0) {
      s_linv[ty] = 1.0f / lr0;
      s_linv[ty + 16] = 1.0f / lr1;
      s_linv[ty + 32] = 1.0f / lr2;
      s_linv[ty + 48] = 1.0f / lr3;
    }
    __syncthreads();

    // ================= pass 2: series write + PV =================
    const float li0 = s_linv[ty];
    const float li1 = s_linv[ty + 16];
    const float li2 = s_linv[ty + 32];
    const float li3 = s_linv[ty + 48];
    float4 acc0 = {0, 0, 0, 0}, acc1 = {0, 0, 0, 0};
    float4 acc2 = {0, 0, 0, 0}, acc3 = {0, 0, 0, 0};
    for (int jt = 0; jt < nt; ++jt) {
      const int j0 = jt * TN;
      __syncthreads();
      for (int idx = t; idx < TN * 16; idx += 256) {
        int r = idx >> 4, c = idx & 15;
        size_t g = (((size_t)b * LL + (j0 + r)) * HH + h) * 16 + c;
        KPs[r][c] = k4[g];
        Vs[r][c] = v4[g];
      }
      __syncthreads();
      float S[4][4] = {};
      for (int e4 = 0; e4 < 16; ++e4) {
        float4 qv0 = Qs[ty][e4];
        float4 qv1 = Qs[ty + 16][e4];
        float4 qv2 = Qs[ty + 32][e4];
        float4 qv3 = Qs[ty + 48][e4];
        float4 kv0 = KPs[tx][e4];
        float4 kv1 = KPs[tx + 16][e4];
        float4 kv2 = KPs[tx + 32][e4];
        float4 kv3 = KPs[tx + 48][e4];
        S[0][0] += dot4(qv0, kv0); S[0][1] += dot4(qv0, kv1);
        S[0][2] += dot4(qv0, kv2); S[0][3] += dot4(qv0, kv3);
        S[1][0] += dot4(qv1, kv0); S[1][1] += dot4(qv1, kv1);
        S[1][2] += dot4(qv1, kv2); S[1][3] += dot4(qv1, kv3);
        S[2][0] += dot4(qv2, kv0); S[2][1] += dot4(qv2, kv1);
        S[2][2] += dot4(qv2, kv2); S[2][3] += dot4(qv2, kv3);
        S[3][0] += dot4(qv3, kv0); S[3][1] += dot4(qv3, kv1);
        S[3][2] += dot4(qv3, kv2); S[3][3] += dot4(qv3, kv3);
      }
      __syncthreads();   // K reads done; safe to overwrite KPs with P
#pragma unroll
      for (int cc = 0; cc < 4; ++cc) {
        int j = j0 + tx + 16 * cc;
        int col = tx + 16 * cc;
        Pf[(ty) * 68 + col]      = (j <= i0 + ty)      ? __expf(S[0][cc] * SCALE) * li0 : 0.f;
        Pf[(ty + 16) * 68 + col] = (j <= i0 + ty + 16) ? __expf(S[1][cc] * SCALE) * li1 : 0.f;
        Pf[(ty + 32) * 68 + col] = (j <= i0 + ty + 32) ? __expf(S[2][cc] * SCALE) * li2 : 0.f;
        Pf[(ty + 48) * 68 + col] = (j <= i0 + ty + 48) ? __expf(S[3][cc] * SCALE) * li3 : 0.f;
      }
      __syncthreads();
      // series tile write: 64 rows x 16 float4, coalesced
#pragma unroll
      for (int m = 0; m < 4; ++m) {
        int idx = t + 256 * m;
        int rr = idx >> 4, jq = idx & 15;
        float4 pv = KPs[rr][jq];
        *(float4*)&out[SERIES_BASE + ((size_t)bh * LL + (i0 + rr)) * LL + j0 + jq * 4] = pv;
      }
      // PV accumulate: rows ty+16*rw, e-chunk tx
#pragma unroll 4
      for (int j4 = 0; j4 < 16; ++j4) {
        float4 p0 = KPs[ty][j4];
        float4 p1 = KPs[ty + 16][j4];
        float4 p2 = KPs[ty + 32][j4];
        float4 p3 = KPs[ty + 48][j4];
        float4 va = Vs[j4 * 4 + 0][tx];
        float4 vb = Vs[j4 * 4 + 1][tx];
        float4 vc = Vs[j4 * 4 + 2][tx];
        float4 vd = Vs[j4 * 4 + 3][tx];
        fma4(acc0, p0.x, va); fma4(acc0, p0.y, vb); fma4(acc0, p0.z, vc); fma4(acc0, p0.w, vd);
        fma4(acc1, p1.x, va); fma4(acc1, p1.y, vb); fma4(acc1, p1.z, vc); fma4(acc1, p1.w, vd);
        fma4(acc2, p2.x, va); fma4(acc2, p2.y, vb); fma4(acc2, p2.z, vc); fma4(acc2, p2.w, vd);
        fma4(acc3, p3.x, va); fma4(acc3, p3.y, vb); fma4(acc3, p3.z, vc); fma4(acc3, p3.w, vd);
      }
    }
    // ---- V output ----
    {
      float4* o4 = (float4*)out;
      o4[(((size_t)b * LL + (i0 + ty)) * HH + h) * 16 + tx] = acc0;
      o4[(((size_t)b * LL + (i0 + ty + 16)) * HH + h) * 16 + tx] = acc1;
      o4[(((size_t)b * LL + (i0 + ty + 32)) * HH + h) * 16 + tx] = acc2;
      o4[(((size_t)b * LL + (i0 + ty + 48)) * HH + h) * 16 + tx] = acc3;
    }
    // ---- prior + sig full rows ----
    for (int idx = t; idx < TM * 512; idx += 256) {
      int rr = idx >> 9, jq = idx & 511;
      float iv = s_pinv[rr], c2 = s_c2[rr], sv = s_sigv[rr];
      float fi = (float)(i0 + rr);
      float d0 = fi - (float)(jq * 4);
      float d1 = d0 - 1.0f, d2 = d0 - 2.0f, d3 = d0 - 3.0f;
      float4 pr;
      pr.x = iv * __expf(-d0 * d0 * c2);
      pr.y = iv * __expf(-d1 * d1 * c2);
      pr.z = iv * __expf(-d2 * d2 * c2);
      pr.w = iv * __expf(-d3 * d3 * c2);
      size_t off = ((size_t)bh * LL + (i0 + rr)) * LL + jq * 4;
      *(float4*)&out[PRIOR_BASE + off] = pr;
      float4 sg4 = {sv, sv, sv, sv};
      *(float4*)&out[SIG_BASE + off] = sg4;
    }
    // ---- series zero-fill (strict upper region beyond causal tiles) ----
    {
      int jz = nt * TN;
      int nz4 = (LL - jz) >> 2;
      if (nz4 > 0) {
        float4 z = {0, 0, 0, 0};
        for (int rr = 0; rr < TM; ++rr) {
          float* rowp = &out[SERIES_BASE + ((size_t)bh * LL + (i0 + rr)) * LL + jz];
          for (int c = t; c < nz4; c += 256) {
            *(float4*)&rowp[c * 4] = z;
          }
        }
      }
    }
  }
}

extern "C" void kernel_launch(void* const* d_in, const int* in_sizes, int n_in,
                              void* d_out, int out_size, void* d_ws, size_t ws_size,
                              hipStream_t stream) {
  const float* q = (const float*)d_in[0];
  const float* k = (const float*)d_in[1];
  const float* v = (const float*)d_in[2];
  const float* sg = (const float*)d_in[3];
  float* out = (float*)d_out;
  dim3 grid(LL / TM / 2, BB * HH);  // 16 x 32 = 512 blocks, uniform work via pairing
  anomaly_attn<<<grid, 256, 0, stream>>>(q, k, v, sg, out);
}

// Round 2
// 1710.800 us; speedup vs baseline: 1.1776x; 1.1776x over previous
//
#include <hip/hip_runtime.h>
#include <math.h>

#define BB 4
#define LL 2048
#define HH 8
#define EE 64
#define TM 64
#define TN 64
#define SH 72   // fp16 LDS row stride: 36 dwords -> 4-bank offset per row (m97 pattern)

typedef _Float16 half4v __attribute__((ext_vector_type(4)));
typedef _Float16 half8v __attribute__((ext_vector_type(8)));
typedef float floatx4 __attribute__((ext_vector_type(4)));

static constexpr float SCALE = 0.125f;                    // 1/sqrt(64)
static constexpr float LN3 = 1.0986122886681098f;
static constexpr float INV_SQRT_2PI = 0.3989422804014327f;
static constexpr size_t NMAT = (size_t)BB * HH * LL * LL;
static constexpr size_t SERIES_BASE = (size_t)BB * LL * HH * EE;
static constexpr size_t PRIOR_BASE = SERIES_BASE + NMAT;
static constexpr size_t SIG_BASE = PRIOR_BASE + NMAT;

__global__ __launch_bounds__(256, 2)
void anomaly_attn(const float* __restrict__ qg,
                  const float* __restrict__ kg,
                  const float* __restrict__ vg,
                  const float* __restrict__ sgg,
                  float* __restrict__ out) {
  __shared__ __attribute__((aligned(16))) _Float16 Qh[TM * SH];
  __shared__ __attribute__((aligned(16))) _Float16 Kh[TN * SH];
  __shared__ __attribute__((aligned(16))) _Float16 Vt[EE * SH];  // transposed: [e][j]
  __shared__ __attribute__((aligned(16))) _Float16 Ph[TM * SH];
  __shared__ float s_sigv[TM], s_pinv[TM], s_c2[TM];

  const int t = threadIdx.x;
  const int lane = t & 63;
  const int w = t >> 6;          // wave id 0..3 -> rows w*16..w*16+15
  const int quad = lane >> 4;    // 0..3
  const int l15 = lane & 15;
  const int bh = blockIdx.y;
  const int b = bh >> 3, h = bh & 7;
  const float4* q4 = (const float4*)qg;
  const float4* k4 = (const float4*)kg;
  const float4* v4 = (const float4*)vg;

  for (int half = 0; half < 2; ++half) {
    const int rt = half ? (31 - (int)blockIdx.x) : (int)blockIdx.x;
    const int i0 = rt * TM;
    const int nt = rt + 1;       // causal j-tiles
    __syncthreads();             // protect LDS/s_* from previous half's readers

    // ---- stage Q (fp32 -> fp16 LDS, row-major) ----
#pragma unroll
    for (int it = 0; it < 4; ++it) {
      int idx = t + 256 * it;
      int r = idx >> 4, c = idx & 15;
      float4 qv = q4[(((size_t)b * LL + i0 + r) * HH + h) * 16 + c];
      half4v hq = {(_Float16)qv.x, (_Float16)qv.y, (_Float16)qv.z, (_Float16)qv.w};
      *(half4v*)&Qh[r * SH + c * 4] = hq;
    }
    // ---- per-row sigma transform ----
    if (t < TM) {
      float sg = sgg[((size_t)b * LL + (i0 + t)) * HH + h];
      float sd = 1.0f / (1.0f + __expf(-5.0f * sg)) + 1e-5f;
      float sv = expm1f(sd * LN3);     // 3^sd - 1, cancellation-safe
      s_sigv[t] = sv;
      s_pinv[t] = INV_SQRT_2PI / sv;
      s_c2[t] = 0.5f / (sv * sv);
    }

    // ================= pass 1: row sums of exp(scale*s) =================
    float lsum[4] = {0.f, 0.f, 0.f, 0.f};
    for (int jt = 0; jt < nt; ++jt) {
      const int j0 = jt * TN;
      __syncthreads();             // prev tile's Kh readers done
#pragma unroll
      for (int it = 0; it < 4; ++it) {
        int idx = t + 256 * it;
        int r = idx >> 4, c = idx & 15;
        float4 kv = k4[(((size_t)b * LL + j0 + r) * HH + h) * 16 + c];
        half4v hk = {(_Float16)kv.x, (_Float16)kv.y, (_Float16)kv.z, (_Float16)kv.w};
        *(half4v*)&Kh[r * SH + c * 4] = hk;
      }
      __syncthreads();
      floatx4 acc[4] = {{0.f, 0.f, 0.f, 0.f}, {0.f, 0.f, 0.f, 0.f},
                        {0.f, 0.f, 0.f, 0.f}, {0.f, 0.f, 0.f, 0.f}};
#pragma unroll
      for (int ks = 0; ks < 2; ++ks) {
        half8v a = *(half8v*)&Qh[(w * 16 + l15) * SH + ks * 32 + quad * 8];
#pragma unroll
        for (int f = 0; f < 4; ++f) {
          half8v bf = *(half8v*)&Kh[(f * 16 + l15) * SH + ks * 32 + quad * 8];
          acc[f] = __builtin_amdgcn_mfma_f32_16x16x32_f16(a, bf, acc[f], 0, 0, 0);
        }
      }
#pragma unroll
      for (int f = 0; f < 4; ++f) {
        int j = j0 + f * 16 + l15;        // C col = lane&15
#pragma unroll
        for (int r = 0; r < 4; ++r) {
          int i = i0 + w * 16 + quad * 4 + r;  // C row = quad*4+reg
          lsum[r] += (j <= i) ? __expf(acc[f][r] * SCALE) : 0.f;
        }
      }
    }
#pragma unroll
    for (int r = 0; r < 4; ++r) {
      lsum[r] += __shfl_xor(lsum[r], 1);
      lsum[r] += __shfl_xor(lsum[r], 2);
      lsum[r] += __shfl_xor(lsum[r], 4);
      lsum[r] += __shfl_xor(lsum[r], 8);
    }
    float linv[4];
#pragma unroll
    for (int r = 0; r < 4; ++r) linv[r] = 1.0f / lsum[r];

    // ================= pass 2: series + PV =================
    floatx4 Oacc[4] = {{0.f, 0.f, 0.f, 0.f}, {0.f, 0.f, 0.f, 0.f},
                       {0.f, 0.f, 0.f, 0.f}, {0.f, 0.f, 0.f, 0.f}};
    for (int jt = 0; jt < nt; ++jt) {
      const int j0 = jt * TN;
      __syncthreads();             // prev tile's Ph/Vt/Kh readers done
#pragma unroll
      for (int it = 0; it < 4; ++it) {
        int idx = t + 256 * it;
        int r = idx >> 4, c = idx & 15;
        float4 kv = k4[(((size_t)b * LL + j0 + r) * HH + h) * 16 + c];
        half4v hk = {(_Float16)kv.x, (_Float16)kv.y, (_Float16)kv.z, (_Float16)kv.w};
        *(half4v*)&Kh[r * SH + c * 4] = hk;
      }
      // V staged transposed: thread (tx=e-group, ty=j-group) does 4x4 micro-transpose
      {
        const int tx = t & 15, ty = t >> 4;
        float4 vv[4];
#pragma unroll
        for (int rr = 0; rr < 4; ++rr)
          vv[rr] = v4[(((size_t)b * LL + j0 + ty * 4 + rr) * HH + h) * 16 + tx];
#pragma unroll
        for (int c = 0; c < 4; ++c) {
          half4v hv = {(_Float16)vv[0].x, (_Float16)vv[1].x, (_Float16)vv[2].x, (_Float16)vv[3].x};
          // select component c
          float e0 = c == 0 ? vv[0].x : c == 1 ? vv[0].y : c == 2 ? vv[0].z : vv[0].w;
          float e1 = c == 0 ? vv[1].x : c == 1 ? vv[1].y : c == 2 ? vv[1].z : vv[1].w;
          float e2 = c == 0 ? vv[2].x : c == 1 ? vv[2].y : c == 2 ? vv[2].z : vv[2].w;
          float e3 = c == 0 ? vv[3].x : c == 1 ? vv[3].y : c == 2 ? vv[3].z : vv[3].w;
          hv = (half4v){(_Float16)e0, (_Float16)e1, (_Float16)e2, (_Float16)e3};
          *(half4v*)&Vt[(tx * 4 + c) * SH + ty * 4] = hv;
        }
      }
      __syncthreads();
      floatx4 acc[4] = {{0.f, 0.f, 0.f, 0.f}, {0.f, 0.f, 0.f, 0.f},
                        {0.f, 0.f, 0.f, 0.f}, {0.f, 0.f, 0.f, 0.f}};
#pragma unroll
      for (int ks = 0; ks < 2; ++ks) {
        half8v a = *(half8v*)&Qh[(w * 16 + l15) * SH + ks * 32 + quad * 8];
#pragma unroll
        for (int f = 0; f < 4; ++f) {
          half8v bf = *(half8v*)&Kh[(f * 16 + l15) * SH + ks * 32 + quad * 8];
          acc[f] = __builtin_amdgcn_mfma_f32_16x16x32_f16(a, bf, acc[f], 0, 0, 0);
        }
      }
      // P = exp(s*scale)*linv (already normalized) -> Ph fp16, C->A layout transform
#pragma unroll
      for (int f = 0; f < 4; ++f) {
        int j = j0 + f * 16 + l15;
#pragma unroll
        for (int r = 0; r < 4; ++r) {
          int i = i0 + w * 16 + quad * 4 + r;
          float p = (j <= i) ? __expf(acc[f][r] * SCALE) * linv[r] : 0.f;
          Ph[(w * 16 + quad * 4 + r) * SH + f * 16 + l15] = (_Float16)p;
        }
      }
      __syncthreads();
      // series tile store: coalesced b128 readback -> 2x float4
#pragma unroll
      for (int rnd = 0; rnd < 2; ++rnd) {
        int idx = t + 256 * rnd;
        int r = idx >> 3, c8 = idx & 7;
        half8v p = *(half8v*)&Ph[r * SH + c8 * 8];
        float4 lo = {(float)p[0], (float)p[1], (float)p[2], (float)p[3]};
        float4 hi = {(float)p[4], (float)p[5], (float)p[6], (float)p[7]};
        size_t off = SERIES_BASE + ((size_t)bh * LL + i0 + r) * LL + j0 + c8 * 8;
        *(float4*)&out[off] = lo;
        *(float4*)&out[off + 4] = hi;
      }
      // PV: O += P * V  (A = Ph rows, B = Vt rows)
#pragma unroll
      for (int ks = 0; ks < 2; ++ks) {
        half8v a = *(half8v*)&Ph[(w * 16 + l15) * SH + ks * 32 + quad * 8];
#pragma unroll
        for (int f = 0; f < 4; ++f) {
          half8v bv = *(half8v*)&Vt[(f * 16 + l15) * SH + ks * 32 + quad * 8];
          Oacc[f] = __builtin_amdgcn_mfma_f32_16x16x32_f16(a, bv, Oacc[f], 0, 0, 0);
        }
      }
    }
    // ---- V output (already normalized) ----
#pragma unroll
    for (int f = 0; f < 4; ++f) {
#pragma unroll
      for (int r = 0; r < 4; ++r) {
        int i = i0 + w * 16 + quad * 4 + r;
        out[(((size_t)b * LL + i) * HH + h) * EE + f * 16 + l15] = Oacc[f][r];
      }
    }
    // ---- prior + sig full rows ----
    for (int idx = t; idx < TM * 512; idx += 256) {
      int rr = idx >> 9, jq = idx & 511;
      float iv = s_pinv[rr], c2 = s_c2[rr], sv = s_sigv[rr];
      float fi = (float)(i0 + rr);
      float d0 = fi - (float)(jq * 4);
      float d1 = d0 - 1.0f, d2 = d0 - 2.0f, d3 = d0 - 3.0f;
      float4 pr;
      pr.x = iv * __expf(-d0 * d0 * c2);
      pr.y = iv * __expf(-d1 * d1 * c2);
      pr.z = iv * __expf(-d2 * d2 * c2);
      pr.w = iv * __expf(-d3 * d3 * c2);
      size_t off = ((size_t)bh * LL + (i0 + rr)) * LL + jq * 4;
      *(float4*)&out[PRIOR_BASE + off] = pr;
      float4 sg4 = {sv, sv, sv, sv};
      *(float4*)&out[SIG_BASE + off] = sg4;
    }
    // ---- series zero-fill (beyond causal tiles) ----
    {
      int jz = nt * TN;
      int nz4 = (LL - jz) >> 2;
      if (nz4 > 0) {
        float4 z = {0, 0, 0, 0};
        for (int rr = 0; rr < TM; ++rr) {
          float* rowp = &out[SERIES_BASE + ((size_t)bh * LL + (i0 + rr)) * LL + jz];
          for (int c = t; c < nz4; c += 256) {
            *(float4*)&rowp[c * 4] = z;
          }
        }
      }
    }
  }
}

extern "C" void kernel_launch(void* const* d_in, const int* in_sizes, int n_in,
                              void* d_out, int out_size, void* d_ws, size_t ws_size,
                              hipStream_t stream) {
  const float* q = (const float*)d_in[0];
  const float* k = (const float*)d_in[1];
  const float* v = (const float*)d_in[2];
  const float* sg = (const float*)d_in[3];
  float* out = (float*)d_out;
  dim3 grid(LL / TM / 2, BB * HH);  // 16 x 32 = 512 blocks, uniform via strip pairing
  anomaly_attn<<<grid, 256, 0, stream>>>(q, k, v, sg, out);
}